// Round 19
// baseline (115.332 us; speedup 1.0000x reference)
//
#include <hip/hip_runtime.h>
#include <hip/hip_bf16.h>

#define IN_DIM 128
#define NUM_HEADS 8
#define OUT_DIM 16

#define BKT_SHIFT 7                       // 128 nodes per bucket
#define BKT_MASK 127
#define NB_MAX 512                        // supports nNodes <= 65536
#define SB_MAX 512                        // max stage blocks (edges <= 1M)
#define SLAB_SHIFT 13                     // 8192 record slots per bucket

typedef unsigned int uint;
typedef unsigned short ushort;
using short8 = __attribute__((ext_vector_type(8))) short;
using f32x4  = __attribute__((ext_vector_type(4))) float;
using u32x2  = __attribute__((ext_vector_type(2))) uint;

// one-instruction pack: low16 = bf16(a), high16 = bf16(b), RNE
__device__ inline uint cvt_pk_bf16(float a, float b) {
    uint r;
    asm("v_cvt_pk_bf16_f32 %0, %1, %2" : "=v"(r) : "v"(a), "v"(b));
    return r;
}

// ---------------- Fused: S1 per-chunk histogram (blocks < sb) + W transpose (blocks >= sb) ----------------
__global__ __launch_bounds__(256) void count_prep(const int* __restrict__ dst,
                                                  int* __restrict__ cntMat,
                                                  const float* __restrict__ WQ,
                                                  const float* __restrict__ WK,
                                                  const float* __restrict__ WV,
                                                  ushort* __restrict__ WT,
                                                  int nEdges, int nb, int sb) {
    const int t = threadIdx.x;

    if ((int)blockIdx.x >= sb) {
        // ---- W transpose+convert: WT[n][k] bf16, n in [0,384) ----
        int tid = (blockIdx.x - sb) * 256 + t;      // 0..6143
        int n = tid >> 4;
        int kg = tid & 15;
        const float* W = (n < 128) ? WQ : (n < 256) ? WK : WV;
        int c = n & 127;
        union { short8 s; uint u[4]; } o;
        #pragma unroll
        for (int j = 0; j < 4; ++j) {
            float v0 = W[(kg * 8 + 2 * j) * 128 + c];
            float v1 = W[(kg * 8 + 2 * j + 1) * 128 + c];
            o.u[j] = cvt_pk_bf16(v0, v1);
        }
        *(short8*)(WT + (size_t)n * 128 + kg * 8) = o.s;
        return;
    }

    __shared__ int cnt[NB_MAX];
    const int blk = blockIdx.x;
    for (int i = t; i < NB_MAX; i += 256) cnt[i] = 0;
    __syncthreads();

    const int e0 = blk * 2048;
    #pragma unroll
    for (int i = 0; i < 2; ++i) {
        int e = e0 + (i * 256 + t) * 4;
        if (e + 3 < nEdges) {
            int4 d4 = *(const int4*)(dst + e);
            atomicAdd(&cnt[d4.x >> BKT_SHIFT], 1);
            atomicAdd(&cnt[d4.y >> BKT_SHIFT], 1);
            atomicAdd(&cnt[d4.z >> BKT_SHIFT], 1);
            atomicAdd(&cnt[d4.w >> BKT_SHIFT], 1);
        } else {
            for (int ee = e; ee < nEdges; ++ee) atomicAdd(&cnt[dst[ee] >> BKT_SHIFT], 1);
        }
    }
    __syncthreads();
    for (int bb = t; bb < nb; bb += 256)
        cntMat[(size_t)blk * NB_MAX + bb] = cnt[bb];
}

// ---------------- S2: per-bucket exclusive scan over stage blocks ----------------
__global__ __launch_bounds__(256) void bucket_base(const int* __restrict__ cntMat,
                                                   int* __restrict__ baseMat,
                                                   int* __restrict__ bucketTotal,
                                                   int sb) {
    __shared__ int wsum[4];
    const int bkt = blockIdx.x;
    const int t = threadIdx.x;
    const int lane = t & 63;
    const int wv = t >> 6;

    int c0 = (2 * t     < sb) ? cntMat[(size_t)(2 * t)     * NB_MAX + bkt] : 0;
    int c1 = (2 * t + 1 < sb) ? cntMat[(size_t)(2 * t + 1) * NB_MAX + bkt] : 0;
    int s = c0 + c1;
    int x = s;
    #pragma unroll
    for (int off = 1; off < 64; off <<= 1) { int y = __shfl_up(x, off); if (lane >= off) x += y; }
    if (lane == 63) wsum[wv] = x;
    __syncthreads();
    if (t == 0) {
        int a = 0;
        #pragma unroll
        for (int w = 0; w < 4; ++w) { int tmp = wsum[w]; wsum[w] = a; a += tmp; }
    }
    __syncthreads();
    int prefix = wsum[wv] + (x - s);

    if (2 * t < sb)     baseMat[(size_t)bkt * SB_MAX + 2 * t]     = prefix;
    if (2 * t + 1 < sb) baseMat[(size_t)bkt * SB_MAX + 2 * t + 1] = prefix + c0;
    if (t == 255) bucketTotal[bkt] = prefix + s;   // grand total
}

// ---------------- S3: scatter records to slab, LDS cursors only (no global atomics) ----------------
__global__ __launch_bounds__(256) void stage_scatter(const int* __restrict__ src,
                                                     const int* __restrict__ dst,
                                                     const int* __restrict__ baseMat,
                                                     uint* __restrict__ slab,
                                                     int nEdges, int nb) {
    __shared__ int base[NB_MAX];
    __shared__ int cur[NB_MAX];
    const int t = threadIdx.x;
    const int blk = blockIdx.x;

    for (int bb = t; bb < nb; bb += 256) {
        base[bb] = baseMat[(size_t)bb * SB_MAX + blk];
        cur[bb] = 0;
    }
    __syncthreads();

    const int e0 = blk * 2048;
    int myDst[8], mySrc[8];
    #pragma unroll
    for (int i = 0; i < 2; ++i) {
        int e = e0 + (i * 256 + t) * 4;
        if (e + 3 < nEdges) {
            int4 d4 = *(const int4*)(dst + e);
            int4 s4 = *(const int4*)(src + e);
            myDst[4*i+0] = d4.x; myDst[4*i+1] = d4.y; myDst[4*i+2] = d4.z; myDst[4*i+3] = d4.w;
            mySrc[4*i+0] = s4.x; mySrc[4*i+1] = s4.y; mySrc[4*i+2] = s4.z; mySrc[4*i+3] = s4.w;
        } else {
            #pragma unroll
            for (int k = 0; k < 4; ++k) {
                int ee = e + k;
                myDst[4*i+k] = (ee < nEdges) ? dst[ee] : -1;
                mySrc[4*i+k] = (ee < nEdges) ? src[ee] : 0;
            }
        }
    }

    #pragma unroll
    for (int i = 0; i < 8; ++i) {
        int d = myDst[i];
        if (d >= 0) {
            int b = d >> BKT_SHIFT;
            int r = atomicAdd(&cur[b], 1);
            slab[((size_t)b << SLAB_SHIFT) + base[b] + r] = (uint)mySrc[i] | ((uint)(d & BKT_MASK) << 17);
        }
    }
}

// ---------------- Fused: bucket_sort (blocks < nb) + MFMA proj (blocks >= nb) ----------------
__global__ __launch_bounds__(64, 2) void sort_proj(const uint* __restrict__ slab,
                                                   const int* __restrict__ bucketTotal,
                                                   int* __restrict__ offsets,
                                                   int* __restrict__ srcSorted,
                                                   const float* __restrict__ h,
                                                   const short* __restrict__ WT,   // [384][128] bf16
                                                   const float* __restrict__ bQ,
                                                   const float* __restrict__ bK,
                                                   const float* __restrict__ bV,
                                                   uint* __restrict__ Qout,        // [N][64] bf16 pairs
                                                   uint* __restrict__ KVout,       // [N][128] K|V pairs
                                                   int nNodes, int nEdges, int nb) {
    const int t = threadIdx.x;

    if ((int)blockIdx.x < nb) {
        // ---- sort: one wave per 128-node bucket ----
        __shared__ int cnt[128];
        __shared__ int sOutBase;
        const int b = blockIdx.x;
        const int count = bucketTotal[b];
        const uint* rec = slab + ((size_t)b << SLAB_SHIFT);

        int acc = 0;
        for (int i = t; i < b; i += 64) acc += bucketTotal[i];
        #pragma unroll
        for (int off = 32; off; off >>= 1) acc += __shfl_down(acc, off);
        if (t == 0) sOutBase = acc;
        cnt[t] = 0; cnt[t + 64] = 0;
        __syncthreads();

        for (int i = t; i < count; i += 64)
            atomicAdd(&cnt[rec[i] >> 17], 1);
        __syncthreads();

        const int outBase = sOutBase;
        int c0 = cnt[2 * t], c1 = cnt[2 * t + 1];
        int s = c0 + c1;
        int x = s;
        #pragma unroll
        for (int off = 1; off < 64; off <<= 1) { int y = __shfl_up(x, off); if (t >= off) x += y; }
        int prefix = x - s;
        int node0 = b << BKT_SHIFT;
        int g0 = node0 + 2 * t, g1 = node0 + 2 * t + 1;
        if (g0 < nNodes) offsets[g0] = outBase + prefix;
        if (g1 < nNodes) offsets[g1] = outBase + prefix + c0;
        __syncthreads();
        cnt[2 * t] = prefix;
        cnt[2 * t + 1] = prefix + c0;
        __syncthreads();

        for (int i = t; i < count; i += 64) {
            uint r = rec[i];
            int pos = atomicAdd(&cnt[r >> 17], 1);
            srcSorted[outBase + pos] = (int)(r & 0x1ffff);
        }
        if (b == 0 && t == 0) offsets[nNodes] = nEdges;
        return;
    }

    // ---- proj: wave = 64 nodes x 4 c-iters; gw>>1 -> node group, gw&1 -> c-half ----
    const int gw = blockIdx.x - nb;
    const int lane = t;
    const int lr = lane & 15;
    const int q = lane >> 4;
    const int node0 = (gw >> 1) * 64;
    const int chalf = gw & 1;

    short8 a[4][4];
    #pragma unroll
    for (int g = 0; g < 4; ++g) {
        const int row = node0 + g * 16 + lr;
        const bool ok = row < nNodes;
        #pragma unroll
        for (int ks = 0; ks < 4; ++ks) {
            union { short8 s; uint u[4]; } v;
            if (ok) {
                const float* p = h + (size_t)row * 128 + (ks * 4 + q) * 8;
                float4 f0 = *(const float4*)p;
                float4 f1 = *(const float4*)(p + 4);
                v.u[0] = cvt_pk_bf16(f0.x, f0.y);
                v.u[1] = cvt_pk_bf16(f0.z, f0.w);
                v.u[2] = cvt_pk_bf16(f1.x, f1.y);
                v.u[3] = cvt_pk_bf16(f1.z, f1.w);
            } else {
                v.s = (short8)0;
            }
            a[g][ks] = v.s;
        }
    }

    const short8* WT8 = (const short8*)WT;   // [384][16]

    #pragma unroll 2
    for (int cc = 0; cc < 4; ++cc) {
        const int c = chalf * 4 + cc;
        const int nq = c * 16 + lr;          // output col 0..127
        f32x4 aQ[4] = {{0,0,0,0},{0,0,0,0},{0,0,0,0},{0,0,0,0}};
        f32x4 aK[4] = {{0,0,0,0},{0,0,0,0},{0,0,0,0},{0,0,0,0}};
        f32x4 aV[4] = {{0,0,0,0},{0,0,0,0},{0,0,0,0},{0,0,0,0}};
        #pragma unroll
        for (int ks = 0; ks < 4; ++ks) {
            short8 bq = WT8[(size_t)nq * 16 + ks * 4 + q];
            short8 bk = WT8[(size_t)(nq + 128) * 16 + ks * 4 + q];
            short8 bv = WT8[(size_t)(nq + 256) * 16 + ks * 4 + q];
            #pragma unroll
            for (int g = 0; g < 4; ++g) {
                aQ[g] = __builtin_amdgcn_mfma_f32_16x16x32_bf16(a[g][ks], bq, aQ[g], 0, 0, 0);
                aK[g] = __builtin_amdgcn_mfma_f32_16x16x32_bf16(a[g][ks], bk, aK[g], 0, 0, 0);
                aV[g] = __builtin_amdgcn_mfma_f32_16x16x32_bf16(a[g][ks], bv, aV[g], 0, 0, 0);
            }
        }
        const float biasq = bQ[nq];
        const float biask = bK[nq];
        const float biasv = bV[nq];
        #pragma unroll
        for (int g = 0; g < 4; ++g) {
            #pragma unroll
            for (int r = 0; r < 4; ++r) {
                int node = node0 + g * 16 + q * 4 + r;
                float qval = aQ[g][r] + biasq;
                float qpart = __shfl_xor(qval, 1);    // partner col (lr^1), same node
                if (node < nNodes) {
                    if ((lr & 1) == 0)
                        Qout[(size_t)node * 64 + (nq >> 1)] = cvt_pk_bf16(qval, qpart);
                    KVout[(size_t)node * 128 + nq] = cvt_pk_bf16(aK[g][r] + biask, aV[g][r] + biasv);
                }
            }
        }
    }
}

// ---------------- Aggregation: one wave per dst node, 2 edges in parallel per wave ----------------
// (R16 proven form: no explicit pipeline, no waves-per-EU clamp — R17's pipelined
//  variant under __launch_bounds__(256,8) spilled to scratch: FETCH +57MB, WRITE +136MB.)
__global__ __launch_bounds__(256) void agg_kernel(const int* __restrict__ offsets,
                                                  const int* __restrict__ srcSorted,
                                                  const uint* __restrict__ Q,     // [N][64] bf16 pairs
                                                  const uint4* __restrict__ KV,   // row = 32 uint4
                                                  float* __restrict__ out,
                                                  int nNodes) {
    int wid = (int)((blockIdx.x * (size_t)blockDim.x + threadIdx.x) >> 6);
    if (wid >= nNodes) return;
    const int lane = threadIdx.x & 63;
    const int li = lane & 31;
    const int hf = lane >> 5;
    const int beg = offsets[wid];
    const int end = offsets[wid + 1];

    u32x2 qp = __builtin_nontemporal_load((const u32x2*)(Q + (size_t)wid * 64) + li);
    f32x4 qv;
    qv.x = __uint_as_float(qp.x << 16);
    qv.y = __uint_as_float(qp.x & 0xffff0000u);
    qv.z = __uint_as_float(qp.y << 16);
    qv.w = __uint_as_float(qp.y & 0xffff0000u);

    f32x4 acc = {0.f, 0.f, 0.f, 0.f};
    float zacc = 0.f;

    auto compute = [&](uint4 u, float mask) {
        float k0 = __uint_as_float(u.x << 16), v0 = __uint_as_float(u.x & 0xffff0000u);
        float k1 = __uint_as_float(u.y << 16), v1 = __uint_as_float(u.y & 0xffff0000u);
        float k2 = __uint_as_float(u.z << 16), v2 = __uint_as_float(u.z & 0xffff0000u);
        float k3 = __uint_as_float(u.w << 16), v3 = __uint_as_float(u.w & 0xffff0000u);
        float p = k0 * qv.x + k1 * qv.y + k2 * qv.z + k3 * qv.w;
        p += __shfl_xor(p, 1);
        p += __shfl_xor(p, 2);
        float e = __expf(fminf(fmaxf(p * 0.25f, -5.0f), 5.0f)) * mask;
        acc.x += v0 * e; acc.y += v1 * e; acc.z += v2 * e; acc.w += v3 * e;
        zacc += e;
    };

    int j = beg;
    for (; j + 8 <= end; j += 8) {
        int sI[4];
        #pragma unroll
        for (int i = 0; i < 4; ++i) sI[i] = __builtin_nontemporal_load(srcSorted + j + 2 * i + hf);
        uint4 u[4];
        #pragma unroll
        for (int i = 0; i < 4; ++i) u[i] = KV[(size_t)sI[i] * 32 + li];
        #pragma unroll
        for (int i = 0; i < 4; ++i) compute(u[i], 1.f);
    }
    for (; j + 2 <= end; j += 2) {
        uint4 u = KV[(size_t)srcSorted[j + hf] * 32 + li];
        compute(u, 1.f);
    }
    if (j < end) {
        uint4 u = KV[(size_t)srcSorted[j] * 32 + li];
        compute(u, hf ? 0.f : 1.f);
    }

    acc.x += __shfl_xor(acc.x, 32);
    acc.y += __shfl_xor(acc.y, 32);
    acc.z += __shfl_xor(acc.z, 32);
    acc.w += __shfl_xor(acc.w, 32);
    zacc  += __shfl_xor(zacc, 32);

    if (hf == 0) {
        float inv = 1.0f / (zacc + 1e-6f);
        f32x4 o = {acc.x * inv, acc.y * inv, acc.z * inv, acc.w * inv};
        __builtin_nontemporal_store(o, (f32x4*)(out + (size_t)wid * 128) + li);
    }
}

extern "C" void kernel_launch(void* const* d_in, const int* in_sizes, int n_in,
                              void* d_out, int out_size, void* d_ws, size_t ws_size,
                              hipStream_t stream) {
    const float* h   = (const float*)d_in[0];
    const int*   src = (const int*)d_in[1];
    const int*   dst = (const int*)d_in[2];
    const float* WQ  = (const float*)d_in[3];
    const float* bQ  = (const float*)d_in[4];
    const float* WK  = (const float*)d_in[5];
    const float* bK  = (const float*)d_in[6];
    const float* WV  = (const float*)d_in[7];
    const float* bV  = (const float*)d_in[8];

    const int nNodes = in_sizes[0] / IN_DIM;
    const int nEdges = in_sizes[1];
    const int nb = (nNodes + (1 << BKT_SHIFT) - 1) >> BKT_SHIFT;   // 391 for 50000
    const int sb = (nEdges + 2047) / 2048;                         // 391 stage chunks

    float* out = (float*)d_out;
    const size_t nf = (size_t)nNodes * 128;

    uint*   Qw         = (uint*)d_ws;                    // nNodes*64 u32 (bf16 pairs)
    uint*   KVw        = Qw + (size_t)nNodes * 64;       // nf u32
    ushort* WTw        = (ushort*)(KVw + nf);            // 384*128 bf16
    int*    bucketTotal= (int*)(WTw + 384 * 128);        // NB_MAX
    int*    offsets    = bucketTotal + NB_MAX;           // nNodes+1
    int*    srcSorted  = offsets + (nNodes + 1);         // nEdges
    uint*   slab       = (uint*)(srcSorted + nEdges);    // NB_MAX << SLAB_SHIFT (16MB)
    int*    cntMat     = (int*)(slab + ((size_t)NB_MAX << SLAB_SHIFT));  // SB_MAX*NB_MAX (1MB)
    int*    baseMat    = cntMat + (size_t)SB_MAX * NB_MAX;               // NB_MAX*SB_MAX (1MB)

    // fused: per-chunk histogram (sb blocks) + W transpose (24 blocks)
    count_prep<<<sb + 24, 256, 0, stream>>>(dst, cntMat, WQ, WK, WV, WTw, nEdges, nb, sb);

    // per-bucket scan, then atomic-free scatter
    bucket_base<<<nb, 256, 0, stream>>>(cntMat, baseMat, bucketTotal, sb);
    stage_scatter<<<sb, 256, 0, stream>>>(src, dst, baseMat, slab, nEdges, nb);

    // fused: sort (nb blocks) + proj (2*ceil(nNodes/64) one-wave blocks)
    int projWaves = ((nNodes + 63) / 64) * 2;            // 1564
    sort_proj<<<nb + projWaves, 64, 0, stream>>>(slab, bucketTotal, offsets, srcSorted,
                                                 h, (const short*)WTw, bQ, bK, bV,
                                                 Qw, KVw, nNodes, nEdges, nb);

    int aggBlocks = (nNodes * 64 + 255) / 256;
    agg_kernel<<<aggBlocks, 256, 0, stream>>>(offsets, srcSorted, Qw, (const uint4*)KVw, out, nNodes);
}

// Round 20
// 114.623 us; speedup vs baseline: 1.0062x; 1.0062x over previous
//
#include <hip/hip_runtime.h>
#include <hip/hip_bf16.h>

#define IN_DIM 128
#define NUM_HEADS 8
#define OUT_DIM 16

#define BKT_SHIFT 7                       // 128 nodes per bucket
#define BKT_MASK 127
#define NB_MAX 512                        // supports nNodes <= 65536
#define SB_MAX 512                        // max stage blocks (edges <= 1M)
#define SLAB_SHIFT 13                     // 8192 record slots per bucket

typedef unsigned int uint;
typedef unsigned short ushort;
using short8 = __attribute__((ext_vector_type(8))) short;
using f32x4  = __attribute__((ext_vector_type(4))) float;
using u32x2  = __attribute__((ext_vector_type(2))) uint;

// one-instruction pack: low16 = bf16(a), high16 = bf16(b), RNE
__device__ inline uint cvt_pk_bf16(float a, float b) {
    uint r;
    asm("v_cvt_pk_bf16_f32 %0, %1, %2" : "=v"(r) : "v"(a), "v"(b));
    return r;
}

// ---------------- Fused: S1 per-chunk histogram (blocks < sb) + W transpose (blocks >= sb) ----------------
__global__ __launch_bounds__(256) void count_prep(const int* __restrict__ dst,
                                                  int* __restrict__ cntMat,
                                                  const float* __restrict__ WQ,
                                                  const float* __restrict__ WK,
                                                  const float* __restrict__ WV,
                                                  ushort* __restrict__ WT,
                                                  int nEdges, int nb, int sb) {
    const int t = threadIdx.x;

    if ((int)blockIdx.x >= sb) {
        // ---- W transpose+convert: WT[n][k] bf16, n in [0,384) ----
        int tid = (blockIdx.x - sb) * 256 + t;      // 0..6143
        int n = tid >> 4;
        int kg = tid & 15;
        const float* W = (n < 128) ? WQ : (n < 256) ? WK : WV;
        int c = n & 127;
        union { short8 s; uint u[4]; } o;
        #pragma unroll
        for (int j = 0; j < 4; ++j) {
            float v0 = W[(kg * 8 + 2 * j) * 128 + c];
            float v1 = W[(kg * 8 + 2 * j + 1) * 128 + c];
            o.u[j] = cvt_pk_bf16(v0, v1);
        }
        *(short8*)(WT + (size_t)n * 128 + kg * 8) = o.s;
        return;
    }

    __shared__ int cnt[NB_MAX];
    const int blk = blockIdx.x;
    for (int i = t; i < NB_MAX; i += 256) cnt[i] = 0;
    __syncthreads();

    const int e0 = blk * 2048;
    #pragma unroll
    for (int i = 0; i < 2; ++i) {
        int e = e0 + (i * 256 + t) * 4;
        if (e + 3 < nEdges) {
            int4 d4 = *(const int4*)(dst + e);
            atomicAdd(&cnt[d4.x >> BKT_SHIFT], 1);
            atomicAdd(&cnt[d4.y >> BKT_SHIFT], 1);
            atomicAdd(&cnt[d4.z >> BKT_SHIFT], 1);
            atomicAdd(&cnt[d4.w >> BKT_SHIFT], 1);
        } else {
            for (int ee = e; ee < nEdges; ++ee) atomicAdd(&cnt[dst[ee] >> BKT_SHIFT], 1);
        }
    }
    __syncthreads();
    for (int bb = t; bb < nb; bb += 256)
        cntMat[(size_t)blk * NB_MAX + bb] = cnt[bb];
}

// ---------------- S2: per-bucket exclusive scan over stage blocks ----------------
__global__ __launch_bounds__(256) void bucket_base(const int* __restrict__ cntMat,
                                                   int* __restrict__ baseMat,
                                                   int* __restrict__ bucketTotal,
                                                   int sb) {
    __shared__ int wsum[4];
    const int bkt = blockIdx.x;
    const int t = threadIdx.x;
    const int lane = t & 63;
    const int wv = t >> 6;

    int c0 = (2 * t     < sb) ? cntMat[(size_t)(2 * t)     * NB_MAX + bkt] : 0;
    int c1 = (2 * t + 1 < sb) ? cntMat[(size_t)(2 * t + 1) * NB_MAX + bkt] : 0;
    int s = c0 + c1;
    int x = s;
    #pragma unroll
    for (int off = 1; off < 64; off <<= 1) { int y = __shfl_up(x, off); if (lane >= off) x += y; }
    if (lane == 63) wsum[wv] = x;
    __syncthreads();
    if (t == 0) {
        int a = 0;
        #pragma unroll
        for (int w = 0; w < 4; ++w) { int tmp = wsum[w]; wsum[w] = a; a += tmp; }
    }
    __syncthreads();
    int prefix = wsum[wv] + (x - s);

    if (2 * t < sb)     baseMat[(size_t)bkt * SB_MAX + 2 * t]     = prefix;
    if (2 * t + 1 < sb) baseMat[(size_t)bkt * SB_MAX + 2 * t + 1] = prefix + c0;
    if (t == 255) bucketTotal[bkt] = prefix + s;   // grand total
}

// ---------------- S3: scatter records to slab, LDS cursors only (no global atomics) ----------------
__global__ __launch_bounds__(256) void stage_scatter(const int* __restrict__ src,
                                                     const int* __restrict__ dst,
                                                     const int* __restrict__ baseMat,
                                                     uint* __restrict__ slab,
                                                     int nEdges, int nb) {
    __shared__ int base[NB_MAX];
    __shared__ int cur[NB_MAX];
    const int t = threadIdx.x;
    const int blk = blockIdx.x;

    for (int bb = t; bb < nb; bb += 256) {
        base[bb] = baseMat[(size_t)bb * SB_MAX + blk];
        cur[bb] = 0;
    }
    __syncthreads();

    const int e0 = blk * 2048;
    int myDst[8], mySrc[8];
    #pragma unroll
    for (int i = 0; i < 2; ++i) {
        int e = e0 + (i * 256 + t) * 4;
        if (e + 3 < nEdges) {
            int4 d4 = *(const int4*)(dst + e);
            int4 s4 = *(const int4*)(src + e);
            myDst[4*i+0] = d4.x; myDst[4*i+1] = d4.y; myDst[4*i+2] = d4.z; myDst[4*i+3] = d4.w;
            mySrc[4*i+0] = s4.x; mySrc[4*i+1] = s4.y; mySrc[4*i+2] = s4.z; mySrc[4*i+3] = s4.w;
        } else {
            #pragma unroll
            for (int k = 0; k < 4; ++k) {
                int ee = e + k;
                myDst[4*i+k] = (ee < nEdges) ? dst[ee] : -1;
                mySrc[4*i+k] = (ee < nEdges) ? src[ee] : 0;
            }
        }
    }

    #pragma unroll
    for (int i = 0; i < 8; ++i) {
        int d = myDst[i];
        if (d >= 0) {
            int b = d >> BKT_SHIFT;
            int r = atomicAdd(&cur[b], 1);
            slab[((size_t)b << SLAB_SHIFT) + base[b] + r] = (uint)mySrc[i] | ((uint)(d & BKT_MASK) << 17);
        }
    }
}

// ---------------- Fused: bucket_sort (blocks < nb) + MFMA proj (blocks >= nb) ----------------
__global__ __launch_bounds__(64, 2) void sort_proj(const uint* __restrict__ slab,
                                                   const int* __restrict__ bucketTotal,
                                                   int* __restrict__ offsets,
                                                   int* __restrict__ srcSorted,
                                                   const float* __restrict__ h,
                                                   const short* __restrict__ WT,   // [384][128] bf16
                                                   const float* __restrict__ bQ,
                                                   const float* __restrict__ bK,
                                                   const float* __restrict__ bV,
                                                   uint* __restrict__ Qout,        // [N][64] bf16 pairs
                                                   uint* __restrict__ KVout,       // [N][128] K|V pairs
                                                   int nNodes, int nEdges, int nb) {
    const int t = threadIdx.x;

    if ((int)blockIdx.x < nb) {
        // ---- sort: one wave per 128-node bucket ----
        __shared__ int cnt[128];
        __shared__ int sOutBase;
        const int b = blockIdx.x;
        const int count = bucketTotal[b];
        const uint* rec = slab + ((size_t)b << SLAB_SHIFT);

        int acc = 0;
        for (int i = t; i < b; i += 64) acc += bucketTotal[i];
        #pragma unroll
        for (int off = 32; off; off >>= 1) acc += __shfl_down(acc, off);
        if (t == 0) sOutBase = acc;
        cnt[t] = 0; cnt[t + 64] = 0;
        __syncthreads();

        for (int i = t; i < count; i += 64)
            atomicAdd(&cnt[rec[i] >> 17], 1);
        __syncthreads();

        const int outBase = sOutBase;
        int c0 = cnt[2 * t], c1 = cnt[2 * t + 1];
        int s = c0 + c1;
        int x = s;
        #pragma unroll
        for (int off = 1; off < 64; off <<= 1) { int y = __shfl_up(x, off); if (t >= off) x += y; }
        int prefix = x - s;
        int node0 = b << BKT_SHIFT;
        int g0 = node0 + 2 * t, g1 = node0 + 2 * t + 1;
        if (g0 < nNodes) offsets[g0] = outBase + prefix;
        if (g1 < nNodes) offsets[g1] = outBase + prefix + c0;
        __syncthreads();
        cnt[2 * t] = prefix;
        cnt[2 * t + 1] = prefix + c0;
        __syncthreads();

        for (int i = t; i < count; i += 64) {
            uint r = rec[i];
            int pos = atomicAdd(&cnt[r >> 17], 1);
            srcSorted[outBase + pos] = (int)(r & 0x1ffff);
        }
        if (b == 0 && t == 0) offsets[nNodes] = nEdges;
        return;
    }

    // ---- proj: wave = 64 nodes x 4 c-iters; gw>>1 -> node group, gw&1 -> c-half ----
    const int gw = blockIdx.x - nb;
    const int lane = t;
    const int lr = lane & 15;
    const int q = lane >> 4;
    const int node0 = (gw >> 1) * 64;
    const int chalf = gw & 1;

    short8 a[4][4];
    #pragma unroll
    for (int g = 0; g < 4; ++g) {
        const int row = node0 + g * 16 + lr;
        const bool ok = row < nNodes;
        #pragma unroll
        for (int ks = 0; ks < 4; ++ks) {
            union { short8 s; uint u[4]; } v;
            if (ok) {
                const float* p = h + (size_t)row * 128 + (ks * 4 + q) * 8;
                float4 f0 = *(const float4*)p;
                float4 f1 = *(const float4*)(p + 4);
                v.u[0] = cvt_pk_bf16(f0.x, f0.y);
                v.u[1] = cvt_pk_bf16(f0.z, f0.w);
                v.u[2] = cvt_pk_bf16(f1.x, f1.y);
                v.u[3] = cvt_pk_bf16(f1.z, f1.w);
            } else {
                v.s = (short8)0;
            }
            a[g][ks] = v.s;
        }
    }

    const short8* WT8 = (const short8*)WT;   // [384][16]

    #pragma unroll 2
    for (int cc = 0; cc < 4; ++cc) {
        const int c = chalf * 4 + cc;
        const int nq = c * 16 + lr;          // output col 0..127
        f32x4 aQ[4] = {{0,0,0,0},{0,0,0,0},{0,0,0,0},{0,0,0,0}};
        f32x4 aK[4] = {{0,0,0,0},{0,0,0,0},{0,0,0,0},{0,0,0,0}};
        f32x4 aV[4] = {{0,0,0,0},{0,0,0,0},{0,0,0,0},{0,0,0,0}};
        #pragma unroll
        for (int ks = 0; ks < 4; ++ks) {
            short8 bq = WT8[(size_t)nq * 16 + ks * 4 + q];
            short8 bk = WT8[(size_t)(nq + 128) * 16 + ks * 4 + q];
            short8 bv = WT8[(size_t)(nq + 256) * 16 + ks * 4 + q];
            #pragma unroll
            for (int g = 0; g < 4; ++g) {
                aQ[g] = __builtin_amdgcn_mfma_f32_16x16x32_bf16(a[g][ks], bq, aQ[g], 0, 0, 0);
                aK[g] = __builtin_amdgcn_mfma_f32_16x16x32_bf16(a[g][ks], bk, aK[g], 0, 0, 0);
                aV[g] = __builtin_amdgcn_mfma_f32_16x16x32_bf16(a[g][ks], bv, aV[g], 0, 0, 0);
            }
        }
        const float biasq = bQ[nq];
        const float biask = bK[nq];
        const float biasv = bV[nq];
        #pragma unroll
        for (int g = 0; g < 4; ++g) {
            #pragma unroll
            for (int r = 0; r < 4; ++r) {
                int node = node0 + g * 16 + q * 4 + r;
                float qval = aQ[g][r] + biasq;
                float qpart = __shfl_xor(qval, 1);    // partner col (lr^1), same node
                if (node < nNodes) {
                    if ((lr & 1) == 0)
                        Qout[(size_t)node * 64 + (nq >> 1)] = cvt_pk_bf16(qval, qpart);
                    KVout[(size_t)node * 128 + nq] = cvt_pk_bf16(aK[g][r] + biask, aV[g][r] + biasv);
                }
            }
        }
    }
}

// ---------------- Aggregation: one wave per dst node, 2 edges in parallel per wave ----------------
// (R16 proven form: no explicit pipeline, no waves-per-EU clamp — R17's pipelined
//  variant under __launch_bounds__(256,8) spilled to scratch: FETCH +57MB, WRITE +136MB.)
__global__ __launch_bounds__(256) void agg_kernel(const int* __restrict__ offsets,
                                                  const int* __restrict__ srcSorted,
                                                  const uint* __restrict__ Q,     // [N][64] bf16 pairs
                                                  const uint4* __restrict__ KV,   // row = 32 uint4
                                                  float* __restrict__ out,
                                                  int nNodes) {
    int wid = (int)((blockIdx.x * (size_t)blockDim.x + threadIdx.x) >> 6);
    if (wid >= nNodes) return;
    const int lane = threadIdx.x & 63;
    const int li = lane & 31;
    const int hf = lane >> 5;
    const int beg = offsets[wid];
    const int end = offsets[wid + 1];

    u32x2 qp = __builtin_nontemporal_load((const u32x2*)(Q + (size_t)wid * 64) + li);
    f32x4 qv;
    qv.x = __uint_as_float(qp.x << 16);
    qv.y = __uint_as_float(qp.x & 0xffff0000u);
    qv.z = __uint_as_float(qp.y << 16);
    qv.w = __uint_as_float(qp.y & 0xffff0000u);

    f32x4 acc = {0.f, 0.f, 0.f, 0.f};
    float zacc = 0.f;

    auto compute = [&](uint4 u, float mask) {
        float k0 = __uint_as_float(u.x << 16), v0 = __uint_as_float(u.x & 0xffff0000u);
        float k1 = __uint_as_float(u.y << 16), v1 = __uint_as_float(u.y & 0xffff0000u);
        float k2 = __uint_as_float(u.z << 16), v2 = __uint_as_float(u.z & 0xffff0000u);
        float k3 = __uint_as_float(u.w << 16), v3 = __uint_as_float(u.w & 0xffff0000u);
        float p = k0 * qv.x + k1 * qv.y + k2 * qv.z + k3 * qv.w;
        p += __shfl_xor(p, 1);
        p += __shfl_xor(p, 2);
        float e = __expf(fminf(fmaxf(p * 0.25f, -5.0f), 5.0f)) * mask;
        acc.x += v0 * e; acc.y += v1 * e; acc.z += v2 * e; acc.w += v3 * e;
        zacc += e;
    };

    int j = beg;
    for (; j + 8 <= end; j += 8) {
        int sI[4];
        #pragma unroll
        for (int i = 0; i < 4; ++i) sI[i] = __builtin_nontemporal_load(srcSorted + j + 2 * i + hf);
        uint4 u[4];
        #pragma unroll
        for (int i = 0; i < 4; ++i) u[i] = KV[(size_t)sI[i] * 32 + li];
        #pragma unroll
        for (int i = 0; i < 4; ++i) compute(u[i], 1.f);
    }
    for (; j + 2 <= end; j += 2) {
        uint4 u = KV[(size_t)srcSorted[j + hf] * 32 + li];
        compute(u, 1.f);
    }
    if (j < end) {
        uint4 u = KV[(size_t)srcSorted[j] * 32 + li];
        compute(u, hf ? 0.f : 1.f);
    }

    acc.x += __shfl_xor(acc.x, 32);
    acc.y += __shfl_xor(acc.y, 32);
    acc.z += __shfl_xor(acc.z, 32);
    acc.w += __shfl_xor(acc.w, 32);
    zacc  += __shfl_xor(zacc, 32);

    if (hf == 0) {
        float inv = 1.0f / (zacc + 1e-6f);
        f32x4 o = {acc.x * inv, acc.y * inv, acc.z * inv, acc.w * inv};
        __builtin_nontemporal_store(o, (f32x4*)(out + (size_t)wid * 128) + li);
    }
}

extern "C" void kernel_launch(void* const* d_in, const int* in_sizes, int n_in,
                              void* d_out, int out_size, void* d_ws, size_t ws_size,
                              hipStream_t stream) {
    const float* h   = (const float*)d_in[0];
    const int*   src = (const int*)d_in[1];
    const int*   dst = (const int*)d_in[2];
    const float* WQ  = (const float*)d_in[3];
    const float* bQ  = (const float*)d_in[4];
    const float* WK  = (const float*)d_in[5];
    const float* bK  = (const float*)d_in[6];
    const float* WV  = (const float*)d_in[7];
    const float* bV  = (const float*)d_in[8];

    const int nNodes = in_sizes[0] / IN_DIM;
    const int nEdges = in_sizes[1];
    const int nb = (nNodes + (1 << BKT_SHIFT) - 1) >> BKT_SHIFT;   // 391 for 50000
    const int sb = (nEdges + 2047) / 2048;                         // 391 stage chunks

    float* out = (float*)d_out;
    const size_t nf = (size_t)nNodes * 128;

    uint*   Qw         = (uint*)d_ws;                    // nNodes*64 u32 (bf16 pairs)
    uint*   KVw        = Qw + (size_t)nNodes * 64;       // nf u32
    ushort* WTw        = (ushort*)(KVw + nf);            // 384*128 bf16
    int*    bucketTotal= (int*)(WTw + 384 * 128);        // NB_MAX
    int*    offsets    = bucketTotal + NB_MAX;           // nNodes+1
    int*    srcSorted  = offsets + (nNodes + 1);         // nEdges
    uint*   slab       = (uint*)(srcSorted + nEdges);    // NB_MAX << SLAB_SHIFT (16MB)
    int*    cntMat     = (int*)(slab + ((size_t)NB_MAX << SLAB_SHIFT));  // SB_MAX*NB_MAX (1MB)
    int*    baseMat    = cntMat + (size_t)SB_MAX * NB_MAX;               // NB_MAX*SB_MAX (1MB)

    // fused: per-chunk histogram (sb blocks) + W transpose (24 blocks)
    count_prep<<<sb + 24, 256, 0, stream>>>(dst, cntMat, WQ, WK, WV, WTw, nEdges, nb, sb);

    // per-bucket scan, then atomic-free scatter
    bucket_base<<<nb, 256, 0, stream>>>(cntMat, baseMat, bucketTotal, sb);
    stage_scatter<<<sb, 256, 0, stream>>>(src, dst, baseMat, slab, nEdges, nb);

    // fused: sort (nb blocks) + proj (2*ceil(nNodes/64) one-wave blocks)
    int projWaves = ((nNodes + 63) / 64) * 2;            // 1564
    sort_proj<<<nb + projWaves, 64, 0, stream>>>(slab, bucketTotal, offsets, srcSorted,
                                                 h, (const short*)WTw, bQ, bK, bV,
                                                 Qw, KVw, nNodes, nEdges, nb);

    int aggBlocks = (nNodes * 64 + 255) / 256;
    agg_kernel<<<aggBlocks, 256, 0, stream>>>(offsets, srcSorted, Qw, (const uint4*)KVw, out, nNodes);
}